// Round 1
// baseline (347.868 us; speedup 1.0000x reference)
//
#include <hip/hip_runtime.h>

#define L_LM 2000
#define F_DIM 64
#define B_SZ 2048

// ---------------- Kernel 1: BMU (argmin of squared distance) ----------------
// One block handles ROWS batch rows. Score = |lm|^2 - 2*x.lm (x^2 is constant
// per row, irrelevant for argmin). Tie-break: lower landmark index (matches
// jnp.argmin first-occurrence).
__global__ __launch_bounds__(256) void som_bmu_kernel(
    const float* __restrict__ x, const float* __restrict__ lm,
    int* __restrict__ min_idx)
{
    constexpr int ROWS = 8;
    const int b0 = blockIdx.x * ROWS;
    const int tid = threadIdx.x;

    __shared__ float xs[ROWS][F_DIM];
    for (int i = tid; i < ROWS * F_DIM; i += 256) {
        xs[i / F_DIM][i % F_DIM] = x[(size_t)(b0 + i / F_DIM) * F_DIM + (i % F_DIM)];
    }
    __syncthreads();

    float best[ROWS];
    int   bidx[ROWS];
#pragma unroll
    for (int r = 0; r < ROWS; ++r) { best[r] = 3.4e38f; bidx[r] = 0; }

    for (int l = tid; l < L_LM; l += 256) {
        const float4* lp = reinterpret_cast<const float4*>(lm + (size_t)l * F_DIM);
        float dot[ROWS];
        float l2 = 0.f;
#pragma unroll
        for (int r = 0; r < ROWS; ++r) dot[r] = 0.f;
#pragma unroll
        for (int k = 0; k < F_DIM / 4; ++k) {
            float4 v = lp[k];
            l2 += v.x * v.x + v.y * v.y + v.z * v.z + v.w * v.w;
#pragma unroll
            for (int r = 0; r < ROWS; ++r) {
                dot[r] += v.x * xs[r][4 * k + 0] + v.y * xs[r][4 * k + 1]
                        + v.z * xs[r][4 * k + 2] + v.w * xs[r][4 * k + 3];
            }
        }
#pragma unroll
        for (int r = 0; r < ROWS; ++r) {
            float s = l2 - 2.f * dot[r];
            if (s < best[r]) { best[r] = s; bidx[r] = l; }  // per-thread l ascending
        }
    }

    // Wave-level reduce (64 lanes), lexicographic (score, index)
#pragma unroll
    for (int r = 0; r < ROWS; ++r) {
        float s = best[r]; int i = bidx[r];
        for (int off = 32; off > 0; off >>= 1) {
            float s2 = __shfl_down(s, off);
            int   i2 = __shfl_down(i, off);
            if (s2 < s || (s2 == s && i2 < i)) { s = s2; i = i2; }
        }
        best[r] = s; bidx[r] = i;
    }

    __shared__ float sbest[4][ROWS];
    __shared__ int   sidx[4][ROWS];
    const int wave = tid >> 6;
    const int lane = tid & 63;
    if (lane == 0) {
#pragma unroll
        for (int r = 0; r < ROWS; ++r) { sbest[wave][r] = best[r]; sidx[wave][r] = bidx[r]; }
    }
    __syncthreads();
    if (tid < ROWS) {
        float s = sbest[0][tid]; int i = sidx[0][tid];
#pragma unroll
        for (int w = 1; w < 4; ++w) {
            float s2 = sbest[w][tid]; int i2 = sidx[w][tid];
            if (s2 < s || (s2 == s && i2 < i)) { s = s2; i = i2; }
        }
        min_idx[b0 + tid] = i;
    }
}

// ---------------- Kernel 2: delta0 write (store-BW bound) ----------------
// out[b][l][f] = qd[min_idx[b]][l] * (x[b][f] - lm[l][f])
// Linear i over (l,f4): float4 address in lm AND out are both i*16B -> fully
// coalesced streaming.
__global__ __launch_bounds__(256) void som_delta_kernel(
    const float* __restrict__ x, const float* __restrict__ lm,
    const float* __restrict__ qd, const int* __restrict__ min_idx,
    float4* __restrict__ out)
{
    const int b = blockIdx.y;
    const int i = blockIdx.x * 256 + threadIdx.x;   // 0 .. 31999
    const int l  = i >> 4;
    const int f4 = i & 15;

    const float h = qd[(size_t)min_idx[b] * L_LM + l];
    const float4 xv = reinterpret_cast<const float4*>(x + (size_t)b * F_DIM)[f4];
    const float4 lv = reinterpret_cast<const float4*>(lm)[i];

    float4 o;
    o.x = h * (xv.x - lv.x);
    o.y = h * (xv.y - lv.y);
    o.z = h * (xv.z - lv.z);
    o.w = h * (xv.w - lv.w);

    out[(size_t)b * (L_LM * F_DIM / 4) + i] = o;
}

extern "C" void kernel_launch(void* const* d_in, const int* in_sizes, int n_in,
                              void* d_out, int out_size, void* d_ws, size_t ws_size,
                              hipStream_t stream) {
    const float* x  = (const float*)d_in[0];
    const float* lm = (const float*)d_in[1];
    const float* qd = (const float*)d_in[2];
    float* out = (float*)d_out;
    int* midx = (int*)d_ws;

    som_bmu_kernel<<<B_SZ / 8, 256, 0, stream>>>(x, lm, midx);

    dim3 grid(L_LM * F_DIM / 4 / 256, B_SZ);  // (125, 2048)
    som_delta_kernel<<<grid, 256, 0, stream>>>(x, lm, qd, midx, (float4*)out);
}

// Round 2
// 280.233 us; speedup vs baseline: 1.2414x; 1.2414x over previous
//
#include <hip/hip_runtime.h>

#define L_LM 2000
#define F_DIM 64
#define B_SZ 2048

typedef float f32x4 __attribute__((ext_vector_type(4)));

// ---------------- Kernel 1: BMU (argmin of squared distance) ----------------
// One block handles ROWS batch rows. Score = |lm|^2 - 2*x.lm (x^2 is constant
// per row, irrelevant for argmin). Tie-break: lower landmark index (matches
// jnp.argmin first-occurrence).
__global__ __launch_bounds__(256) void som_bmu_kernel(
    const float* __restrict__ x, const float* __restrict__ lm,
    int* __restrict__ min_idx)
{
    constexpr int ROWS = 8;
    const int b0 = blockIdx.x * ROWS;
    const int tid = threadIdx.x;

    __shared__ float xs[ROWS][F_DIM];
    for (int i = tid; i < ROWS * F_DIM; i += 256) {
        xs[i / F_DIM][i % F_DIM] = x[(size_t)(b0 + i / F_DIM) * F_DIM + (i % F_DIM)];
    }
    __syncthreads();

    float best[ROWS];
    int   bidx[ROWS];
#pragma unroll
    for (int r = 0; r < ROWS; ++r) { best[r] = 3.4e38f; bidx[r] = 0; }

    for (int l = tid; l < L_LM; l += 256) {
        const float4* lp = reinterpret_cast<const float4*>(lm + (size_t)l * F_DIM);
        float dot[ROWS];
        float l2 = 0.f;
#pragma unroll
        for (int r = 0; r < ROWS; ++r) dot[r] = 0.f;
#pragma unroll
        for (int k = 0; k < F_DIM / 4; ++k) {
            float4 v = lp[k];
            l2 += v.x * v.x + v.y * v.y + v.z * v.z + v.w * v.w;
#pragma unroll
            for (int r = 0; r < ROWS; ++r) {
                dot[r] += v.x * xs[r][4 * k + 0] + v.y * xs[r][4 * k + 1]
                        + v.z * xs[r][4 * k + 2] + v.w * xs[r][4 * k + 3];
            }
        }
#pragma unroll
        for (int r = 0; r < ROWS; ++r) {
            float s = l2 - 2.f * dot[r];
            if (s < best[r]) { best[r] = s; bidx[r] = l; }  // per-thread l ascending
        }
    }

    // Wave-level reduce (64 lanes), lexicographic (score, index)
#pragma unroll
    for (int r = 0; r < ROWS; ++r) {
        float s = best[r]; int i = bidx[r];
        for (int off = 32; off > 0; off >>= 1) {
            float s2 = __shfl_down(s, off);
            int   i2 = __shfl_down(i, off);
            if (s2 < s || (s2 == s && i2 < i)) { s = s2; i = i2; }
        }
        best[r] = s; bidx[r] = i;
    }

    __shared__ float sbest[4][ROWS];
    __shared__ int   sidx[4][ROWS];
    const int wave = tid >> 6;
    const int lane = tid & 63;
    if (lane == 0) {
#pragma unroll
        for (int r = 0; r < ROWS; ++r) { sbest[wave][r] = best[r]; sidx[wave][r] = bidx[r]; }
    }
    __syncthreads();
    if (tid < ROWS) {
        float s = sbest[0][tid]; int i = sidx[0][tid];
#pragma unroll
        for (int w = 1; w < 4; ++w) {
            float s2 = sbest[w][tid]; int i2 = sidx[w][tid];
            if (s2 < s || (s2 == s && i2 < i)) { s = s2; i = i2; }
        }
        min_idx[b0 + tid] = i;
    }
}

// ---------------- Kernel 2: delta0 write (store-BW bound) ----------------
// out[b][l][f] = qd[min_idx[b]][l] * (x[b][f] - lm[l][f])
// Persistent: one block per batch row b; 256 threads loop 125x over the
// 32000 float4s of the row. min_idx[b] and the x fragment (tid&15 is
// loop-invariant) hoisted; output stores nontemporal (streaming, no reuse).
__global__ __launch_bounds__(256) void som_delta_kernel(
    const float* __restrict__ x, const float* __restrict__ lm,
    const float* __restrict__ qd, const int* __restrict__ min_idx,
    f32x4* __restrict__ out)
{
    constexpr int ROW4 = L_LM * F_DIM / 4;  // 32000 float4 per batch row
    const int b = blockIdx.x;
    const int tid = threadIdx.x;

    const int bmu = min_idx[b];                       // uniform per block
    const float* __restrict__ qrow = qd + (size_t)bmu * L_LM;
    const f32x4 xv = reinterpret_cast<const f32x4*>(x + (size_t)b * F_DIM)[tid & 15];
    const f32x4* __restrict__ lmv = reinterpret_cast<const f32x4*>(lm);
    f32x4* __restrict__ ob = out + (size_t)b * ROW4;

#pragma unroll 5
    for (int i = tid; i < ROW4; i += 256) {
        const int l = i >> 4;
        const float h = qrow[l];
        const f32x4 lv = lmv[i];
        f32x4 o;
        o.x = h * (xv.x - lv.x);
        o.y = h * (xv.y - lv.y);
        o.z = h * (xv.z - lv.z);
        o.w = h * (xv.w - lv.w);
        __builtin_nontemporal_store(o, &ob[i]);
    }
}

extern "C" void kernel_launch(void* const* d_in, const int* in_sizes, int n_in,
                              void* d_out, int out_size, void* d_ws, size_t ws_size,
                              hipStream_t stream) {
    const float* x  = (const float*)d_in[0];
    const float* lm = (const float*)d_in[1];
    const float* qd = (const float*)d_in[2];
    float* out = (float*)d_out;
    int* midx = (int*)d_ws;

    som_bmu_kernel<<<B_SZ / 8, 256, 0, stream>>>(x, lm, midx);

    som_delta_kernel<<<B_SZ, 256, 0, stream>>>(x, lm, qd, midx, (f32x4*)out);
}

// Round 3
// 261.089 us; speedup vs baseline: 1.3324x; 1.0733x over previous
//
#include <hip/hip_runtime.h>

#define L_LM 2000
#define F_DIM 64
#define B_SZ 2048
#define CL 16      // landmarks per delta block
#define CB 128     // batch rows per delta block

typedef float f32x4 __attribute__((ext_vector_type(4)));

// ---------------- Kernel 1: BMU (argmin of squared distance) ----------------
// One block handles ROWS batch rows. Score = |lm|^2 - 2*x.lm (x^2 is constant
// per row, irrelevant for argmin). Tie-break: lower landmark index (matches
// jnp.argmin first-occurrence).
__global__ __launch_bounds__(256) void som_bmu_kernel(
    const float* __restrict__ x, const float* __restrict__ lm,
    int* __restrict__ min_idx)
{
    constexpr int ROWS = 8;
    const int b0 = blockIdx.x * ROWS;
    const int tid = threadIdx.x;

    __shared__ float xs[ROWS][F_DIM];
    for (int i = tid; i < ROWS * F_DIM; i += 256) {
        xs[i / F_DIM][i % F_DIM] = x[(size_t)(b0 + i / F_DIM) * F_DIM + (i % F_DIM)];
    }
    __syncthreads();

    float best[ROWS];
    int   bidx[ROWS];
#pragma unroll
    for (int r = 0; r < ROWS; ++r) { best[r] = 3.4e38f; bidx[r] = 0; }

    for (int l = tid; l < L_LM; l += 256) {
        const float4* lp = reinterpret_cast<const float4*>(lm + (size_t)l * F_DIM);
        float dot[ROWS];
        float l2 = 0.f;
#pragma unroll
        for (int r = 0; r < ROWS; ++r) dot[r] = 0.f;
#pragma unroll
        for (int k = 0; k < F_DIM / 4; ++k) {
            float4 v = lp[k];
            l2 += v.x * v.x + v.y * v.y + v.z * v.z + v.w * v.w;
#pragma unroll
            for (int r = 0; r < ROWS; ++r) {
                dot[r] += v.x * xs[r][4 * k + 0] + v.y * xs[r][4 * k + 1]
                        + v.z * xs[r][4 * k + 2] + v.w * xs[r][4 * k + 3];
            }
        }
#pragma unroll
        for (int r = 0; r < ROWS; ++r) {
            float s = l2 - 2.f * dot[r];
            if (s < best[r]) { best[r] = s; bidx[r] = l; }  // per-thread l ascending
        }
    }

    // Wave-level reduce (64 lanes), lexicographic (score, index)
#pragma unroll
    for (int r = 0; r < ROWS; ++r) {
        float s = best[r]; int i = bidx[r];
        for (int off = 32; off > 0; off >>= 1) {
            float s2 = __shfl_down(s, off);
            int   i2 = __shfl_down(i, off);
            if (s2 < s || (s2 == s && i2 < i)) { s = s2; i = i2; }
        }
        best[r] = s; bidx[r] = i;
    }

    __shared__ float sbest[4][ROWS];
    __shared__ int   sidx[4][ROWS];
    const int wave = tid >> 6;
    const int lane = tid & 63;
    if (lane == 0) {
#pragma unroll
        for (int r = 0; r < ROWS; ++r) { sbest[wave][r] = best[r]; sidx[wave][r] = bidx[r]; }
    }
    __syncthreads();
    if (tid < ROWS) {
        float s = sbest[0][tid]; int i = sidx[0][tid];
#pragma unroll
        for (int w = 1; w < 4; ++w) {
            float s2 = sbest[w][tid]; int i2 = sidx[w][tid];
            if (s2 < s || (s2 == s && i2 < i)) { s = s2; i = i2; }
        }
        min_idx[b0 + tid] = i;
    }
}

// ---------------- Kernel 2: delta0 write (store-BW bound) ----------------
// out[b][l][f] = qd[min_idx[b]][l] * (x[b][f] - lm[l][f])
// Tile: block = (CL=16 landmarks) x (CB=128 batch rows). Each thread keeps
// its lm float4 fragment in a REGISTER (chunk = 256 float4 = blockDim), so lm
// is read from HBM/L2 only once per block (8 MB aggregate vs ~1 GB before —
// the store stream thrashes L2, so any per-iteration global read was coming
// from HBM). x rows + h weights staged in LDS. Inner loop: LDS reads + FMA +
// coalesced nontemporal float4 store only.
__global__ __launch_bounds__(256) void som_delta_kernel(
    const float* __restrict__ x, const float* __restrict__ lm,
    const float* __restrict__ qd, const int* __restrict__ min_idx,
    float* __restrict__ out)
{
    const int l0 = blockIdx.x * CL;
    const int b0 = blockIdx.y * CB;
    const int tid = threadIdx.x;
    const int f4 = tid & 15;   // float4 index within feature dim
    const int lg = tid >> 4;   // landmark offset within chunk (0..15)

    __shared__ float xs[CB][F_DIM];   // 32 KB
    __shared__ float hs[CB][CL];      // 8 KB
    __shared__ int   bmu[CB];         // 0.5 KB

    // stage x rows (coalesced float4)
    {
        const f32x4* src = reinterpret_cast<const f32x4*>(x + (size_t)b0 * F_DIM);
        f32x4* dst = reinterpret_cast<f32x4*>(&xs[0][0]);
        for (int i = tid; i < CB * F_DIM / 4; i += 256) dst[i] = src[i];
    }
    if (tid < CB) bmu[tid] = min_idx[b0 + tid];

    // thread's private landmark fragment (one float4 per thread covers chunk)
    const f32x4 lv = reinterpret_cast<const f32x4*>(lm + (size_t)(l0 + lg) * F_DIM)[f4];

    __syncthreads();

    // stage h: hs[b][j] = qd[bmu[b]][l0+j]  (64 B contiguous per b)
    for (int i = tid; i < CB * CL; i += 256) {
        const int b = i >> 4, j = i & 15;
        hs[b][j] = qd[(size_t)bmu[b] * L_LM + l0 + j];
    }
    __syncthreads();

    float* ob = out + (size_t)b0 * (L_LM * F_DIM) + (size_t)l0 * F_DIM;
#pragma unroll 4
    for (int b = 0; b < CB; ++b) {
        const float h = hs[b][lg];
        const f32x4 xv = reinterpret_cast<const f32x4*>(&xs[b][0])[f4];
        f32x4 o;
        o.x = h * (xv.x - lv.x);
        o.y = h * (xv.y - lv.y);
        o.z = h * (xv.z - lv.z);
        o.w = h * (xv.w - lv.w);
        __builtin_nontemporal_store(
            o, reinterpret_cast<f32x4*>(ob + (size_t)b * (L_LM * F_DIM)) + tid);
    }
}

extern "C" void kernel_launch(void* const* d_in, const int* in_sizes, int n_in,
                              void* d_out, int out_size, void* d_ws, size_t ws_size,
                              hipStream_t stream) {
    const float* x  = (const float*)d_in[0];
    const float* lm = (const float*)d_in[1];
    const float* qd = (const float*)d_in[2];
    float* out = (float*)d_out;
    int* midx = (int*)d_ws;

    som_bmu_kernel<<<B_SZ / 8, 256, 0, stream>>>(x, lm, midx);

    dim3 grid(L_LM / CL, B_SZ / CB);   // (125, 16) = 2000 blocks
    som_delta_kernel<<<grid, 256, 0, stream>>>(x, lm, qd, midx, out);
}